// Round 5
// baseline (550.021 us; speedup 1.0000x reference)
//
#include <hip/hip_runtime.h>
#include <hip/hip_bf16.h>
#include <stdint.h>

typedef unsigned short u16;
typedef __attribute__((ext_vector_type(8))) __bf16 bf16x8;
typedef __attribute__((ext_vector_type(4))) float f32x4;
typedef __attribute__((ext_vector_type(4))) unsigned short u16x4;

#define B_   16
#define N_   512
#define D_   512
#define H_   8
#define DH_  64
#define HID_ 2048
#define M_   8192   // B_*N_

__device__ __forceinline__ u16 f2bf(float f) {
    unsigned u = __float_as_uint(f);
    u += 0x7fffu + ((u >> 16) & 1u);
    return (u16)(u >> 16);
}
__device__ __forceinline__ float bf2f(u16 u) {
    return __uint_as_float(((unsigned)u) << 16);
}
__device__ __forceinline__ f32x4 mfma16(bf16x8 a, bf16x8 b, f32x4 c) {
    return __builtin_amdgcn_mfma_f32_16x16x32_bf16(a, b, c, 0, 0, 0);
}
__device__ __forceinline__ void gload_lds16(const u16* g, u16* l) {
    __builtin_amdgcn_global_load_lds(
        (const __attribute__((address_space(1))) void*)g,
        (__attribute__((address_space(3))) void*)l, 16, 0, 0);
}

// ---------------------------------------------------------------- convert
__device__ __forceinline__ void cvt4(const float* s, u16* d) {
    f32x4 v = *(const f32x4*)s;
    u16x4 o;
    o[0] = f2bf(v[0]); o[1] = f2bf(v[1]); o[2] = f2bf(v[2]); o[3] = f2bf(v[3]);
    *(u16x4*)d = o;
}
// split f32 -> bf16 hi + bf16 lo (hi+lo represents x to ~2^-18 rel)
__device__ __forceinline__ void cvt4s(const float* s, u16* dh, u16* dl) {
    f32x4 v = *(const f32x4*)s;
    u16x4 oh, ol;
#pragma unroll
    for (int j = 0; j < 4; j++) {
        oh[j] = f2bf(v[j]);
        float r = v[j] - bf2f(oh[j]);
        ol[j] = f2bf(r);
    }
    *(u16x4*)dh = oh;
    *(u16x4*)dl = ol;
}

__global__ __launch_bounds__(256) void convert_all(
    const float* __restrict__ nf, const float* __restrict__ Wq,
    const float* __restrict__ Wk, const float* __restrict__ Wv,
    const float* __restrict__ Wo, const float* __restrict__ W1,
    const float* __restrict__ W2, const float* __restrict__ bq,
    const float* __restrict__ bk, const float* __restrict__ bv,
    u16* __restrict__ xh, u16* __restrict__ xl,
    u16* __restrict__ wqh, u16* __restrict__ wql,
    u16* __restrict__ wob, u16* __restrict__ w1b, u16* __restrict__ w2b,
    float* __restrict__ bqkv)
{
    long i = ((long)blockIdx.x * 256 + threadIdx.x) * 4;
    if (i < 4194304) { cvt4s(nf + i, xh + i, xl + i); return; }
    i -= 4194304;
    if (i < 786432) {
        const float* s = (i < 262144) ? (Wq + i)
                       : (i < 524288) ? (Wk + i - 262144) : (Wv + i - 524288);
        cvt4s(s, wqh + i, wql + i); return;
    }
    i -= 786432;
    if (i < 262144) { cvt4(Wo + i, wob + i); return; }
    i -= 262144;
    if (i < 1048576) { cvt4(W1 + i, w1b + i); return; }
    i -= 1048576;
    if (i < 1048576) { cvt4(W2 + i, w2b + i); return; }
    i -= 1048576;
    if (i < 1536) {
        const float* s = (i < 512) ? (bq + i) : (i < 1024 ? bk + i - 512 : bv + i - 1024);
        *(f32x4*)(bqkv + i) = *(const f32x4*)s;
    }
}

#define BM 128
#define BN 128
#define BK 32

// ------------------------------------------------- split-precision QKV GEMM
// C = A * W^T with A = Ah+Al, W = Wh+Wl (bf16 pairs); acc = AhWh + AhWl + AlWh.
// M=8192, N=1536, K=512. Epilogue: Q,K -> (hi,lo) bf16 pairs; V -> bf16 transposed.
__global__ __launch_bounds__(256) void gemm_qkv(
    const u16* __restrict__ Ah, const u16* __restrict__ Al,
    const u16* __restrict__ Wh, const u16* __restrict__ Wl,
    const float* __restrict__ bias,
    u16* __restrict__ Qh, u16* __restrict__ Ql,
    u16* __restrict__ Kh, u16* __restrict__ Kl, u16* __restrict__ Vt)
{
    __shared__ u16 sAh[BM * BK], sAl[BM * BK], sBh[BN * BK], sBl[BN * BK];
    const int Kdim = 512;
    const int tid = threadIdx.x;
    const int w = tid >> 6, lane = tid & 63;
    const int lr = lane & 15, lg = lane >> 4;
    const int nTn = 1536 / BN;
    const int tm = blockIdx.x / nTn, tn = blockIdx.x % nTn;
    const long m0 = (long)tm * BM, n0 = (long)tn * BN;

    f32x4 acc[4][4];
#pragma unroll
    for (int i = 0; i < 4; i++)
#pragma unroll
        for (int j = 0; j < 4; j++) acc[i][j] = (f32x4){0.f, 0.f, 0.f, 0.f};

    const int e0 = w * 512 + lane * 8;
    const int r0 = e0 >> 5, c0 = e0 & 31;
    const int r1 = r0 + 64;
    const long gA0 = (long)r0 * Kdim + c0, gA1 = (long)r1 * Kdim + c0;
    const u16* pAh = Ah + m0 * Kdim;
    const u16* pAl = Al + m0 * Kdim;
    const u16* pBh = Wh + n0 * Kdim;
    const u16* pBl = Wl + n0 * Kdim;
    u16* dAh0 = sAh + w * 512; u16* dAh1 = sAh + w * 512 + 2048;
    u16* dAl0 = sAl + w * 512; u16* dAl1 = sAl + w * 512 + 2048;
    u16* dBh0 = sBh + w * 512; u16* dBh1 = sBh + w * 512 + 2048;
    u16* dBl0 = sBl + w * 512; u16* dBl1 = sBl + w * 512 + 2048;

    const int wr = (w >> 1) * 64, wc = (w & 1) * 64;

    for (int k0 = 0; k0 < Kdim; k0 += BK) {
        gload_lds16(pAh + gA0 + k0, dAh0);
        gload_lds16(pAh + gA1 + k0, dAh1);
        gload_lds16(pAl + gA0 + k0, dAl0);
        gload_lds16(pAl + gA1 + k0, dAl1);
        gload_lds16(pBh + gA0 + k0, dBh0);
        gload_lds16(pBh + gA1 + k0, dBh1);
        gload_lds16(pBl + gA0 + k0, dBl0);
        gload_lds16(pBl + gA1 + k0, dBl1);
        __syncthreads();
        bf16x8 ah[4], al[4], bh[4], bl[4];
#pragma unroll
        for (int i = 0; i < 4; i++) {
            int ra = (wr + i * 16 + lr) * BK + lg * 8;
            int rb = (wc + i * 16 + lr) * BK + lg * 8;
            ah[i] = *reinterpret_cast<const bf16x8*>(&sAh[ra]);
            al[i] = *reinterpret_cast<const bf16x8*>(&sAl[ra]);
            bh[i] = *reinterpret_cast<const bf16x8*>(&sBh[rb]);
            bl[i] = *reinterpret_cast<const bf16x8*>(&sBl[rb]);
        }
#pragma unroll
        for (int i = 0; i < 4; i++)
#pragma unroll
            for (int j = 0; j < 4; j++) {
                acc[i][j] = mfma16(ah[i], bh[j], acc[i][j]);
                acc[i][j] = mfma16(ah[i], bl[j], acc[i][j]);
                acc[i][j] = mfma16(al[i], bh[j], acc[i][j]);
            }
        __syncthreads();
    }

#pragma unroll
    for (int i = 0; i < 4; i++) {
#pragma unroll
        for (int j = 0; j < 4; j++) {
#pragma unroll
            for (int r = 0; r < 4; r++) {
                long m = m0 + wr + i * 16 + lg * 4 + r;
                long n = n0 + wc + j * 16 + lr;
                float v = acc[i][j][r] + bias[n];
                int b = (int)(m >> 9), nn = (int)(m & 511);
                int which = (int)(n >> 9);
                int h = ((int)n >> 6) & 7, dh = (int)n & 63;
                long bh_ = (long)b * 8 + h;
                if (which == 2) {
                    Vt[(bh_ * 64 + dh) * 512 + nn] = f2bf(v);
                } else {
                    u16 hi = f2bf(v);
                    u16 lo = f2bf(v - bf2f(hi));
                    long idx = (bh_ * 512 + nn) * 64 + dh;
                    if (which == 0) { Qh[idx] = hi; Ql[idx] = lo; }
                    else            { Kh[idx] = hi; Kl[idx] = lo; }
                }
            }
        }
    }
}

// ---------------------------------------------------------------- GEMM (bf16)
// C[M,N] = A[M,K] * W[N,K]^T. EPI: 1 = f32 out (acc+bias+resid), 2 = bf16 relu
template<int EPI>
__global__ __launch_bounds__(256) void gemm_bt(
    const u16* __restrict__ A, const u16* __restrict__ W,
    const float* __restrict__ bias, const float* __restrict__ resid,
    float* __restrict__ outf, u16* __restrict__ outb,
    int Mdim, int Ndim, int Kdim)
{
    __shared__ u16 As[BM * BK];
    __shared__ u16 Bs[BN * BK];
    const int tid = threadIdx.x;
    const int w = tid >> 6, lane = tid & 63;
    const int lr = lane & 15, lg = lane >> 4;
    const int nTn = Ndim / BN;
    const int tm = blockIdx.x / nTn, tn = blockIdx.x % nTn;
    const long m0 = (long)tm * BM, n0 = (long)tn * BN;

    f32x4 acc[4][4];
#pragma unroll
    for (int i = 0; i < 4; i++)
#pragma unroll
        for (int j = 0; j < 4; j++) acc[i][j] = (f32x4){0.f, 0.f, 0.f, 0.f};

    const int e0 = w * 512 + lane * 8;
    const int r0 = e0 >> 5, c0 = e0 & 31;
    const int r1 = r0 + 64, c1 = c0;
    u16* As0 = As + w * 512;
    u16* As1 = As + w * 512 + 2048;
    u16* Bs0 = Bs + w * 512;
    u16* Bs1 = Bs + w * 512 + 2048;
    const u16* Ag = A + m0 * Kdim;
    const u16* Bg = W + n0 * Kdim;

    const int wr = (w >> 1) * 64, wc = (w & 1) * 64;

    for (int k0 = 0; k0 < Kdim; k0 += BK) {
        gload_lds16(Ag + (long)r0 * Kdim + k0 + c0, As0);
        gload_lds16(Ag + (long)r1 * Kdim + k0 + c1, As1);
        gload_lds16(Bg + (long)r0 * Kdim + k0 + c0, Bs0);
        gload_lds16(Bg + (long)r1 * Kdim + k0 + c1, Bs1);
        __syncthreads();
        bf16x8 af[4], bfr[4];
#pragma unroll
        for (int i = 0; i < 4; i++) {
            af[i]  = *reinterpret_cast<const bf16x8*>(&As[(wr + i * 16 + lr) * BK + lg * 8]);
            bfr[i] = *reinterpret_cast<const bf16x8*>(&Bs[(wc + i * 16 + lr) * BK + lg * 8]);
        }
#pragma unroll
        for (int i = 0; i < 4; i++)
#pragma unroll
            for (int j = 0; j < 4; j++)
                acc[i][j] = mfma16(af[i], bfr[j], acc[i][j]);
        __syncthreads();
    }

#pragma unroll
    for (int i = 0; i < 4; i++) {
#pragma unroll
        for (int j = 0; j < 4; j++) {
#pragma unroll
            for (int r = 0; r < 4; r++) {
                long m = m0 + wr + i * 16 + lg * 4 + r;
                long n = n0 + wc + j * 16 + lr;
                float v = acc[i][j][r];
                if (EPI == 1) {
                    long idx = m * Ndim + n;
                    outf[idx] = v + bias[n] + resid[idx];
                } else {
                    float t = v + bias[n];
                    t = t > 0.f ? t : 0.f;
                    outb[m * Ndim + n] = f2bf(t);
                }
            }
        }
    }
}

// ---------------------------------------------------------------- attention
#define PSS 136   // padded LDS stride for P tile

__global__ __launch_bounds__(256) void attn_kernel(
    const u16* __restrict__ Qh, const u16* __restrict__ Ql,
    const u16* __restrict__ Kh, const u16* __restrict__ Kl,
    const u16* __restrict__ Vt,
    const float* __restrict__ bias, const int* __restrict__ mask,
    u16* __restrict__ ctx)
{
    __shared__ u16 Ps[4 * 32 * PSS];
    const int tid = threadIdx.x;
    const int w = tid >> 6, lane = tid & 63;
    const int lr = lane & 15, lg = lane >> 4;
    const int bid = blockIdx.x;
    const int qt = bid & 3;
    const int h  = (bid >> 2) & 7;
    const int b  = bid >> 5;
    const int q0 = qt * 128 + w * 32;
    const long bh = (long)b * 8 + h;
    const u16* Qhp = Qh + bh * 512 * 64;
    const u16* Qlp = Ql + bh * 512 * 64;
    const u16* Khp = Kh + bh * 512 * 64;
    const u16* Klp = Kl + bh * 512 * 64;
    const u16* Vp  = Vt + bh * 64 * 512;
    const float* biasp = bias + (long)b * 512 * 512 * 8 + h;
    const int* maskp = mask + (long)b * 512 * 512;

    bf16x8 qh[2][2], ql[2][2];
#pragma unroll
    for (int mf = 0; mf < 2; mf++)
#pragma unroll
        for (int kk = 0; kk < 2; kk++) {
            long off = (long)(q0 + mf * 16 + lr) * 64 + kk * 32 + lg * 8;
            qh[mf][kk] = *reinterpret_cast<const bf16x8*>(&Qhp[off]);
            ql[mf][kk] = *reinterpret_cast<const bf16x8*>(&Qlp[off]);
        }

    f32x4 of[2][4];
    float m_run[2][4], l_run[2][4];
#pragma unroll
    for (int mf = 0; mf < 2; mf++) {
#pragma unroll
        for (int df = 0; df < 4; df++) of[mf][df] = (f32x4){0.f, 0.f, 0.f, 0.f};
#pragma unroll
        for (int r = 0; r < 4; r++) { m_run[mf][r] = -1e30f; l_run[mf][r] = 0.f; }
    }

    u16* Pw = Ps + w * 32 * PSS;

    for (int kt = 0; kt < 4; ++kt) {
        const int k0 = kt * 128;
        f32x4 s[2][8];
#pragma unroll
        for (int mf = 0; mf < 2; mf++)
#pragma unroll
            for (int kf = 0; kf < 8; kf++) s[mf][kf] = (f32x4){0.f, 0.f, 0.f, 0.f};

#pragma unroll
        for (int kf = 0; kf < 8; kf++) {
            long ko = (long)(k0 + kf * 16 + lr) * 64 + lg * 8;
            bf16x8 kh0 = *reinterpret_cast<const bf16x8*>(&Khp[ko]);
            bf16x8 kh1 = *reinterpret_cast<const bf16x8*>(&Khp[ko + 32]);
            bf16x8 kl0 = *reinterpret_cast<const bf16x8*>(&Klp[ko]);
            bf16x8 kl1 = *reinterpret_cast<const bf16x8*>(&Klp[ko + 32]);
#pragma unroll
            for (int mf = 0; mf < 2; mf++) {
                s[mf][kf] = mfma16(qh[mf][0], kh0, s[mf][kf]);
                s[mf][kf] = mfma16(qh[mf][1], kh1, s[mf][kf]);
                s[mf][kf] = mfma16(qh[mf][0], kl0, s[mf][kf]);
                s[mf][kf] = mfma16(qh[mf][1], kl1, s[mf][kf]);
                s[mf][kf] = mfma16(ql[mf][0], kh0, s[mf][kf]);
                s[mf][kf] = mfma16(ql[mf][1], kh1, s[mf][kf]);
            }
        }
        // scale, bias, mask
#pragma unroll
        for (int mf = 0; mf < 2; mf++) {
#pragma unroll
            for (int r = 0; r < 4; r++) {
                int q = q0 + mf * 16 + lg * 4 + r;
                const float* bprow = biasp + (long)q * 512 * 8;
                const int* mrow = maskp + (long)q * 512;
#pragma unroll
                for (int kf = 0; kf < 8; kf++) {
                    int k = k0 + kf * 16 + lr;
                    float sv = s[mf][kf][r] * 8.0f + bprow[(long)k * 8];
                    if (mrow[k]) sv = -1e30f;
                    s[mf][kf][r] = sv;
                }
            }
        }
        // online softmax per row
#pragma unroll
        for (int mf = 0; mf < 2; mf++) {
#pragma unroll
            for (int r = 0; r < 4; r++) {
                float pm = s[mf][0][r];
#pragma unroll
                for (int kf = 1; kf < 8; kf++) pm = fmaxf(pm, s[mf][kf][r]);
                pm = fmaxf(pm, __shfl_xor(pm, 1));
                pm = fmaxf(pm, __shfl_xor(pm, 2));
                pm = fmaxf(pm, __shfl_xor(pm, 4));
                pm = fmaxf(pm, __shfl_xor(pm, 8));
                float mn = fmaxf(m_run[mf][r], pm);
                float fac = __expf(m_run[mf][r] - mn);
                m_run[mf][r] = mn;
                float rs = 0.f;
#pragma unroll
                for (int kf = 0; kf < 8; kf++) {
                    float p = __expf(s[mf][kf][r] - mn);
                    s[mf][kf][r] = p;
                    rs += p;
                }
                rs += __shfl_xor(rs, 1); rs += __shfl_xor(rs, 2);
                rs += __shfl_xor(rs, 4); rs += __shfl_xor(rs, 8);
                l_run[mf][r] = l_run[mf][r] * fac + rs;
#pragma unroll
                for (int df = 0; df < 4; df++) of[mf][df][r] *= fac;
            }
        }
        // P -> LDS (wave-private region)
#pragma unroll
        for (int mf = 0; mf < 2; mf++)
#pragma unroll
            for (int kf = 0; kf < 8; kf++)
#pragma unroll
                for (int r = 0; r < 4; r++)
                    Pw[(mf * 16 + lg * 4 + r) * PSS + kf * 16 + lr] = f2bf(s[mf][kf][r]);
        // PV
#pragma unroll
        for (int kk = 0; kk < 4; kk++) {
            bf16x8 pa[2];
#pragma unroll
            for (int mf = 0; mf < 2; mf++)
                pa[mf] = *reinterpret_cast<const bf16x8*>(
                    &Pw[(mf * 16 + lr) * PSS + kk * 32 + lg * 8]);
#pragma unroll
            for (int df = 0; df < 4; df++) {
                bf16x8 vb = *reinterpret_cast<const bf16x8*>(
                    &Vp[(long)(df * 16 + lr) * 512 + k0 + kk * 32 + lg * 8]);
                of[0][df] = mfma16(pa[0], vb, of[0][df]);
                of[1][df] = mfma16(pa[1], vb, of[1][df]);
            }
        }
    }
    // epilogue
#pragma unroll
    for (int mf = 0; mf < 2; mf++) {
#pragma unroll
        for (int r = 0; r < 4; r++) {
            int q = q0 + mf * 16 + lg * 4 + r;
            float inv = 1.0f / l_run[mf][r];
            u16* crow = ctx + ((long)b * 512 + q) * 512 + h * 64;
#pragma unroll
            for (int df = 0; df < 4; df++)
                crow[df * 16 + lr] = f2bf(of[mf][df][r] * inv);
        }
    }
}

// ---------------------------------------------------------------- layernorm
template<int WB>
__global__ __launch_bounds__(256) void ln_kernel(
    const float* __restrict__ xin, const float* __restrict__ g,
    const float* __restrict__ bta, float* __restrict__ fout, u16* __restrict__ bout)
{
    const int tid = threadIdx.x;
    const int w = tid >> 6, lane = tid & 63;
    const long row = (long)blockIdx.x * 4 + w;
    const float* xp = xin + row * 512 + lane * 8;
    f32x4 v0 = *(const f32x4*)(xp);
    f32x4 v1 = *(const f32x4*)(xp + 4);
    float sum = v0[0] + v0[1] + v0[2] + v0[3] + v1[0] + v1[1] + v1[2] + v1[3];
    float sq = v0[0]*v0[0] + v0[1]*v0[1] + v0[2]*v0[2] + v0[3]*v0[3]
             + v1[0]*v1[0] + v1[1]*v1[1] + v1[2]*v1[2] + v1[3]*v1[3];
#pragma unroll
    for (int m = 1; m <= 32; m <<= 1) {
        sum += __shfl_xor(sum, m);
        sq  += __shfl_xor(sq, m);
    }
    float mu = sum * (1.f / 512.f);
    float var = sq * (1.f / 512.f) - mu * mu;
    float rstd = rsqrtf(var + 1e-5f);
#pragma unroll
    for (int j = 0; j < 8; j++) {
        int c = lane * 8 + j;
        float x = (j < 4) ? v0[j] : v1[j - 4];
        float y = (x - mu) * rstd * g[c] + bta[c];
        fout[row * 512 + c] = y;
        if (WB) bout[row * 512 + c] = f2bf(y);
    }
}

// ---------------------------------------------------------------- launch
extern "C" void kernel_launch(void* const* d_in, const int* in_sizes, int n_in,
                              void* d_out, int out_size, void* d_ws, size_t ws_size,
                              hipStream_t stream)
{
    const float* nfeat     = (const float*)d_in[0];
    const float* attn_bias = (const float*)d_in[1];
    const int*   attn_mask = (const int*)d_in[2];
    const float* Wq = (const float*)d_in[3];
    const float* bq = (const float*)d_in[4];
    const float* Wk = (const float*)d_in[5];
    const float* bk = (const float*)d_in[6];
    const float* Wv = (const float*)d_in[7];
    const float* bv = (const float*)d_in[8];
    const float* Wo = (const float*)d_in[9];
    const float* bo = (const float*)d_in[10];
    const float* W1 = (const float*)d_in[11];
    const float* b1 = (const float*)d_in[12];
    const float* W2 = (const float*)d_in[13];
    const float* b2 = (const float*)d_in[14];
    const float* ln1_g = (const float*)d_in[15];
    const float* ln1_b = (const float*)d_in[16];
    const float* ln2_g = (const float*)d_in[17];
    const float* ln2_b = (const float*)d_in[18];

    char* ws = (char*)d_ws;
    size_t off = 0;
    auto alloc = [&](size_t bytes) -> void* {
        void* p = ws + off;
        off += (bytes + 255) & ~(size_t)255;
        return p;
    };
    u16* xh    = (u16*)alloc((size_t)M_ * D_ * 2);
    u16* xl    = (u16*)alloc((size_t)M_ * D_ * 2);
    u16* wqh   = (u16*)alloc((size_t)1536 * 512 * 2);
    u16* wql   = (u16*)alloc((size_t)1536 * 512 * 2);
    u16* wob   = (u16*)alloc((size_t)512 * 512 * 2);
    u16* w1b   = (u16*)alloc((size_t)2048 * 512 * 2);
    u16* w2b   = (u16*)alloc((size_t)512 * 2048 * 2);
    float* bqkv = (float*)alloc(1536 * 4);
    u16* Qh    = (u16*)alloc((size_t)B_ * H_ * N_ * DH_ * 2);
    u16* Ql    = (u16*)alloc((size_t)B_ * H_ * N_ * DH_ * 2);
    u16* Kh    = (u16*)alloc((size_t)B_ * H_ * N_ * DH_ * 2);
    u16* Kl    = (u16*)alloc((size_t)B_ * H_ * N_ * DH_ * 2);
    u16* Vt    = (u16*)alloc((size_t)B_ * H_ * N_ * DH_ * 2);
    u16* ctx   = (u16*)alloc((size_t)M_ * D_ * 2);
    float* xres = (float*)alloc((size_t)M_ * D_ * 4);
    float* x1f  = (float*)alloc((size_t)M_ * D_ * 4);
    u16* x1b   = (u16*)alloc((size_t)M_ * D_ * 2);
    u16* hb    = (u16*)alloc((size_t)M_ * HID_ * 2);

    convert_all<<<7170, 256, 0, stream>>>(nfeat, Wq, Wk, Wv, Wo, W1, W2, bq, bk, bv,
                                          xh, xl, wqh, wql, wob, w1b, w2b, bqkv);
    // QKV projection (split precision): M=8192, N=1536, K=512
    gemm_qkv<<<(M_/BM) * (1536/BN), 256, 0, stream>>>(
        xh, xl, wqh, wql, bqkv, Qh, Ql, Kh, Kl, Vt);
    // attention (f32-accurate scores via hi/lo QK^T)
    attn_kernel<<<B_ * H_ * 4, 256, 0, stream>>>(
        Qh, Ql, Kh, Kl, Vt, attn_bias, attn_mask, ctx);
    // out projection + residual: M=8192, N=512, K=512 -> f32 xres
    gemm_bt<1><<<(M_/BM) * (512/BN), 256, 0, stream>>>(
        ctx, wob, bo, nfeat, xres, nullptr, M_, 512, 512);
    // LN1 -> x1f (f32) + x1b (bf16)
    ln_kernel<1><<<M_ / 4, 256, 0, stream>>>(xres, ln1_g, ln1_b, x1f, x1b);
    // FFN1: M=8192, N=2048, K=512 -> relu -> hb (bf16)
    gemm_bt<2><<<(M_/BM) * (HID_/BN), 256, 0, stream>>>(
        x1b, w1b, b1, nullptr, nullptr, hb, M_, HID_, 512);
    // FFN2: M=8192, N=512, K=2048 -> + x1f residual -> xres (f32)
    gemm_bt<1><<<(M_/BM) * (512/BN), 256, 0, stream>>>(
        hb, w2b, b2, x1f, xres, nullptr, M_, 512, 2048);
    // LN2 -> d_out (f32)
    ln_kernel<0><<<M_ / 4, 256, 0, stream>>>(xres, ln2_g, ln2_b, (float*)d_out, nullptr);
}

// Round 6
// 516.503 us; speedup vs baseline: 1.0649x; 1.0649x over previous
//
#include <hip/hip_runtime.h>
#include <hip/hip_bf16.h>
#include <stdint.h>

typedef unsigned short u16;
typedef __attribute__((ext_vector_type(8))) __bf16 bf16x8;
typedef __attribute__((ext_vector_type(4))) float f32x4;
typedef __attribute__((ext_vector_type(4))) unsigned short u16x4;

#define B_   16
#define N_   512
#define D_   512
#define H_   8
#define DH_  64
#define HID_ 2048
#define M_   8192   // B_*N_

__device__ __forceinline__ u16 f2bf(float f) {
    unsigned u = __float_as_uint(f);
    u += 0x7fffu + ((u >> 16) & 1u);
    return (u16)(u >> 16);
}
__device__ __forceinline__ float bf2f(u16 u) {
    return __uint_as_float(((unsigned)u) << 16);
}
__device__ __forceinline__ f32x4 mfma16(bf16x8 a, bf16x8 b, f32x4 c) {
    return __builtin_amdgcn_mfma_f32_16x16x32_bf16(a, b, c, 0, 0, 0);
}
__device__ __forceinline__ void gload_lds16(const u16* g, u16* l) {
    __builtin_amdgcn_global_load_lds(
        (const __attribute__((address_space(1))) void*)g,
        (__attribute__((address_space(3))) void*)l, 16, 0, 0);
}

// ---------------------------------------------------------------- convert
__device__ __forceinline__ void cvt4(const float* s, u16* d) {
    f32x4 v = *(const f32x4*)s;
    u16x4 o;
    o[0] = f2bf(v[0]); o[1] = f2bf(v[1]); o[2] = f2bf(v[2]); o[3] = f2bf(v[3]);
    *(u16x4*)d = o;
}
// split f32 -> bf16 hi + bf16 lo
__device__ __forceinline__ void cvt4s(const float* s, u16* dh, u16* dl) {
    f32x4 v = *(const f32x4*)s;
    u16x4 oh, ol;
#pragma unroll
    for (int j = 0; j < 4; j++) {
        oh[j] = f2bf(v[j]);
        float r = v[j] - bf2f(oh[j]);
        ol[j] = f2bf(r);
    }
    *(u16x4*)dh = oh;
    *(u16x4*)dl = ol;
}

__global__ __launch_bounds__(256) void convert_all(
    const float* __restrict__ nf, const float* __restrict__ Wq,
    const float* __restrict__ Wk, const float* __restrict__ Wv,
    const float* __restrict__ Wo, const float* __restrict__ W1,
    const float* __restrict__ W2, const float* __restrict__ bq,
    const float* __restrict__ bk, const float* __restrict__ bv,
    u16* __restrict__ xh, u16* __restrict__ xl,
    u16* __restrict__ wqh, u16* __restrict__ wql,
    u16* __restrict__ wob, u16* __restrict__ w1b, u16* __restrict__ w2b,
    float* __restrict__ bqkv)
{
    long i = ((long)blockIdx.x * 256 + threadIdx.x) * 4;
    if (i < 4194304) { cvt4s(nf + i, xh + i, xl + i); return; }
    i -= 4194304;
    if (i < 786432) {
        const float* s = (i < 262144) ? (Wq + i)
                       : (i < 524288) ? (Wk + i - 262144) : (Wv + i - 524288);
        cvt4s(s, wqh + i, wql + i); return;
    }
    i -= 786432;
    if (i < 262144) { cvt4(Wo + i, wob + i); return; }
    i -= 262144;
    if (i < 1048576) { cvt4(W1 + i, w1b + i); return; }
    i -= 1048576;
    if (i < 1048576) { cvt4(W2 + i, w2b + i); return; }
    i -= 1048576;
    if (i < 1536) {
        const float* s = (i < 512) ? (bq + i) : (i < 1024 ? bk + i - 512 : bv + i - 1024);
        *(f32x4*)(bqkv + i) = *(const f32x4*)s;
    }
}

#define BM 128
#define BN 128
#define BK 32

// ------------------------------------------------- split-precision QKV GEMM
// Q,K blocks: 3-term hi/lo MFMA; V blocks (which==2, block-uniform): 1-term.
__global__ __launch_bounds__(256) void gemm_qkv(
    const u16* __restrict__ Ah, const u16* __restrict__ Al,
    const u16* __restrict__ Wh, const u16* __restrict__ Wl,
    const float* __restrict__ bias,
    u16* __restrict__ Qh, u16* __restrict__ Ql,
    u16* __restrict__ Kh, u16* __restrict__ Kl, u16* __restrict__ Vt)
{
    __shared__ u16 sAh[BM * BK], sAl[BM * BK], sBh[BN * BK], sBl[BN * BK];
    const int Kdim = 512;
    const int tid = threadIdx.x;
    const int w = tid >> 6, lane = tid & 63;
    const int lr = lane & 15, lg = lane >> 4;
    const int nTn = 1536 / BN;
    const int tm = blockIdx.x / nTn, tn = blockIdx.x % nTn;
    const long m0 = (long)tm * BM, n0 = (long)tn * BN;
    const int which = (int)(n0 >> 9);      // 0=Q 1=K 2=V, block-uniform
    const bool vpath = (which == 2);

    f32x4 acc[4][4];
#pragma unroll
    for (int i = 0; i < 4; i++)
#pragma unroll
        for (int j = 0; j < 4; j++) acc[i][j] = (f32x4){0.f, 0.f, 0.f, 0.f};

    const int e0 = w * 512 + lane * 8;
    const int r0 = e0 >> 5, c0 = e0 & 31;
    const int r1 = r0 + 64;
    const long gA0 = (long)r0 * Kdim + c0, gA1 = (long)r1 * Kdim + c0;
    const u16* pAh = Ah + m0 * Kdim;
    const u16* pAl = Al + m0 * Kdim;
    const u16* pBh = Wh + n0 * Kdim;
    const u16* pBl = Wl + n0 * Kdim;
    u16* dAh0 = sAh + w * 512; u16* dAh1 = sAh + w * 512 + 2048;
    u16* dAl0 = sAl + w * 512; u16* dAl1 = sAl + w * 512 + 2048;
    u16* dBh0 = sBh + w * 512; u16* dBh1 = sBh + w * 512 + 2048;
    u16* dBl0 = sBl + w * 512; u16* dBl1 = sBl + w * 512 + 2048;

    const int wr = (w >> 1) * 64, wc = (w & 1) * 64;

    for (int k0 = 0; k0 < Kdim; k0 += BK) {
        gload_lds16(pAh + gA0 + k0, dAh0);
        gload_lds16(pAh + gA1 + k0, dAh1);
        gload_lds16(pBh + gA0 + k0, dBh0);
        gload_lds16(pBh + gA1 + k0, dBh1);
        if (!vpath) {
            gload_lds16(pAl + gA0 + k0, dAl0);
            gload_lds16(pAl + gA1 + k0, dAl1);
            gload_lds16(pBl + gA0 + k0, dBl0);
            gload_lds16(pBl + gA1 + k0, dBl1);
        }
        __syncthreads();
        bf16x8 ah[4], bh[4];
#pragma unroll
        for (int i = 0; i < 4; i++) {
            int ra = (wr + i * 16 + lr) * BK + lg * 8;
            int rb = (wc + i * 16 + lr) * BK + lg * 8;
            ah[i] = *reinterpret_cast<const bf16x8*>(&sAh[ra]);
            bh[i] = *reinterpret_cast<const bf16x8*>(&sBh[rb]);
        }
        if (vpath) {
#pragma unroll
            for (int i = 0; i < 4; i++)
#pragma unroll
                for (int j = 0; j < 4; j++)
                    acc[i][j] = mfma16(ah[i], bh[j], acc[i][j]);
        } else {
            bf16x8 al[4], bl[4];
#pragma unroll
            for (int i = 0; i < 4; i++) {
                int ra = (wr + i * 16 + lr) * BK + lg * 8;
                int rb = (wc + i * 16 + lr) * BK + lg * 8;
                al[i] = *reinterpret_cast<const bf16x8*>(&sAl[ra]);
                bl[i] = *reinterpret_cast<const bf16x8*>(&sBl[rb]);
            }
#pragma unroll
            for (int i = 0; i < 4; i++)
#pragma unroll
                for (int j = 0; j < 4; j++) {
                    acc[i][j] = mfma16(ah[i], bh[j], acc[i][j]);
                    acc[i][j] = mfma16(ah[i], bl[j], acc[i][j]);
                    acc[i][j] = mfma16(al[i], bh[j], acc[i][j]);
                }
        }
        __syncthreads();
    }

#pragma unroll
    for (int i = 0; i < 4; i++) {
#pragma unroll
        for (int j = 0; j < 4; j++) {
#pragma unroll
            for (int r = 0; r < 4; r++) {
                long m = m0 + wr + i * 16 + lg * 4 + r;
                long n = n0 + wc + j * 16 + lr;
                float v = acc[i][j][r] + bias[n];
                int b = (int)(m >> 9), nn = (int)(m & 511);
                int h = ((int)n >> 6) & 7, dh = (int)n & 63;
                long bh_ = (long)b * 8 + h;
                if (which == 2) {
                    Vt[(bh_ * 64 + dh) * 512 + nn] = f2bf(v);
                } else {
                    u16 hi = f2bf(v);
                    u16 lo = f2bf(v - bf2f(hi));
                    long idx = (bh_ * 512 + nn) * 64 + dh;
                    if (which == 0) { Qh[idx] = hi; Ql[idx] = lo; }
                    else            { Kh[idx] = hi; Kl[idx] = lo; }
                }
            }
        }
    }
}

// ---------------------------------------------------------------- GEMM (bf16)
template<int EPI>
__global__ __launch_bounds__(256) void gemm_bt(
    const u16* __restrict__ A, const u16* __restrict__ W,
    const float* __restrict__ bias, const float* __restrict__ resid,
    float* __restrict__ outf, u16* __restrict__ outb,
    int Mdim, int Ndim, int Kdim)
{
    __shared__ u16 As[BM * BK];
    __shared__ u16 Bs[BN * BK];
    const int tid = threadIdx.x;
    const int w = tid >> 6, lane = tid & 63;
    const int lr = lane & 15, lg = lane >> 4;
    const int nTn = Ndim / BN;
    const int tm = blockIdx.x / nTn, tn = blockIdx.x % nTn;
    const long m0 = (long)tm * BM, n0 = (long)tn * BN;

    f32x4 acc[4][4];
#pragma unroll
    for (int i = 0; i < 4; i++)
#pragma unroll
        for (int j = 0; j < 4; j++) acc[i][j] = (f32x4){0.f, 0.f, 0.f, 0.f};

    const int e0 = w * 512 + lane * 8;
    const int r0 = e0 >> 5, c0 = e0 & 31;
    const int r1 = r0 + 64, c1 = c0;
    u16* As0 = As + w * 512;
    u16* As1 = As + w * 512 + 2048;
    u16* Bs0 = Bs + w * 512;
    u16* Bs1 = Bs + w * 512 + 2048;
    const u16* Ag = A + m0 * Kdim;
    const u16* Bg = W + n0 * Kdim;

    const int wr = (w >> 1) * 64, wc = (w & 1) * 64;

    for (int k0 = 0; k0 < Kdim; k0 += BK) {
        gload_lds16(Ag + (long)r0 * Kdim + k0 + c0, As0);
        gload_lds16(Ag + (long)r1 * Kdim + k0 + c1, As1);
        gload_lds16(Bg + (long)r0 * Kdim + k0 + c0, Bs0);
        gload_lds16(Bg + (long)r1 * Kdim + k0 + c1, Bs1);
        __syncthreads();
        bf16x8 af[4], bfr[4];
#pragma unroll
        for (int i = 0; i < 4; i++) {
            af[i]  = *reinterpret_cast<const bf16x8*>(&As[(wr + i * 16 + lr) * BK + lg * 8]);
            bfr[i] = *reinterpret_cast<const bf16x8*>(&Bs[(wc + i * 16 + lr) * BK + lg * 8]);
        }
#pragma unroll
        for (int i = 0; i < 4; i++)
#pragma unroll
            for (int j = 0; j < 4; j++)
                acc[i][j] = mfma16(af[i], bfr[j], acc[i][j]);
        __syncthreads();
    }

#pragma unroll
    for (int i = 0; i < 4; i++) {
#pragma unroll
        for (int j = 0; j < 4; j++) {
#pragma unroll
            for (int r = 0; r < 4; r++) {
                long m = m0 + wr + i * 16 + lg * 4 + r;
                long n = n0 + wc + j * 16 + lr;
                float v = acc[i][j][r];
                if (EPI == 1) {
                    long idx = m * Ndim + n;
                    outf[idx] = v + bias[n] + resid[idx];
                } else {
                    float t = v + bias[n];
                    t = t > 0.f ? t : 0.f;
                    outb[m * Ndim + n] = f2bf(t);
                }
            }
        }
    }
}

// ---------------------------------------------------------------- attention
// Block = (b, 32-row q-tile); 8 waves, wave w = head w. Bias staged reg->LDS
// coalesced (f32x4 covers 4 heads), mask folded in (-3e38). KT=64.
#define PLST 2116   // per-head bias plane stride in f32 ([32][66] + 4 pad)
#define PST  72     // P LDS row stride (u16)

__global__ __launch_bounds__(512) void attn_kernel(
    const u16* __restrict__ Qh, const u16* __restrict__ Ql,
    const u16* __restrict__ Kh, const u16* __restrict__ Kl,
    const u16* __restrict__ Vt,
    const float* __restrict__ bias, const int* __restrict__ mask,
    u16* __restrict__ ctx)
{
    __shared__ float Bs[8 * PLST];      // 67712 B
    __shared__ u16 Ps[8 * 32 * PST];    // 36864 B
    const int tid = threadIdx.x;
    const int w = tid >> 6, lane = tid & 63;
    const int lr = lane & 15, lg = lane >> 4;
    const int b = blockIdx.x >> 4, qt = blockIdx.x & 15;
    const int bq0 = qt * 32;
    const long bh = (long)b * 8 + w;    // wave w == head w
    const u16* Qhp = Qh + bh * 512 * 64;
    const u16* Qlp = Ql + bh * 512 * 64;
    const u16* Khp = Kh + bh * 512 * 64;
    const u16* Klp = Kl + bh * 512 * 64;
    const u16* Vp  = Vt + bh * 64 * 512;

    // staging ids: thread -> (q-row sq, 16-slot st)
    const int sq = tid >> 4, st = tid & 15;
    const float* bias_row = bias + ((long)b * 512 + bq0 + sq) * 512 * 8;
    const int*   mask_row = mask + ((long)b * 512 + bq0 + sq) * 512;

    bf16x8 qhf[2][2], qlf[2][2];
#pragma unroll
    for (int mf = 0; mf < 2; mf++)
#pragma unroll
        for (int kk = 0; kk < 2; kk++) {
            long off = (long)(bq0 + mf * 16 + lr) * 64 + kk * 32 + lg * 8;
            qhf[mf][kk] = *reinterpret_cast<const bf16x8*>(&Qhp[off]);
            qlf[mf][kk] = *reinterpret_cast<const bf16x8*>(&Qlp[off]);
        }

    f32x4 of[2][4];
    float m_run[2][4], l_run[2][4];
#pragma unroll
    for (int mf = 0; mf < 2; mf++) {
#pragma unroll
        for (int df = 0; df < 4; df++) of[mf][df] = (f32x4){0.f, 0.f, 0.f, 0.f};
#pragma unroll
        for (int r = 0; r < 4; r++) { m_run[mf][r] = -1e30f; l_run[mf][r] = 0.f; }
    }

    float* Bw = Bs + w * PLST;          // this wave's head plane
    u16* Pw = Ps + w * 32 * PST;

    for (int kt = 0; kt < 8; ++kt) {
        const int k0 = kt * 64;
        // (1) issue coalesced bias/mask loads (f32x4 = 4 heads of one (q,k))
        f32x4 breg[8];
        int mreg[8];
#pragma unroll
        for (int j = 0; j < 8; j++) {
            int f = st + j * 16;                      // 0..127
            breg[j] = *(const f32x4*)(bias_row + (long)k0 * 8 + f * 4);
            mreg[j] = mask_row[k0 + (f >> 1)];
        }
        // (2) QK^T (hi/lo 3-term per operand half) — overlaps bias latency
        f32x4 s[2][4];
#pragma unroll
        for (int mf = 0; mf < 2; mf++)
#pragma unroll
            for (int kf = 0; kf < 4; kf++) s[mf][kf] = (f32x4){0.f, 0.f, 0.f, 0.f};
#pragma unroll
        for (int kf = 0; kf < 4; kf++) {
            long ko = (long)(k0 + kf * 16 + lr) * 64 + lg * 8;
            bf16x8 kh0 = *reinterpret_cast<const bf16x8*>(&Khp[ko]);
            bf16x8 kh1 = *reinterpret_cast<const bf16x8*>(&Khp[ko + 32]);
            bf16x8 kl0 = *reinterpret_cast<const bf16x8*>(&Klp[ko]);
            bf16x8 kl1 = *reinterpret_cast<const bf16x8*>(&Klp[ko + 32]);
#pragma unroll
            for (int mf = 0; mf < 2; mf++) {
                s[mf][kf] = mfma16(qhf[mf][0], kh0, s[mf][kf]);
                s[mf][kf] = mfma16(qhf[mf][1], kh1, s[mf][kf]);
                s[mf][kf] = mfma16(qhf[mf][0], kl0, s[mf][kf]);
                s[mf][kf] = mfma16(qhf[mf][1], kl1, s[mf][kf]);
                s[mf][kf] = mfma16(qlf[mf][0], kh0, s[mf][kf]);
                s[mf][kf] = mfma16(qlf[mf][1], kh1, s[mf][kf]);
            }
        }
        // (3) previous consumers done -> safe to overwrite bias LDS
        __syncthreads();
        // (4) regs -> LDS [h][q][k], mask folded
#pragma unroll
        for (int j = 0; j < 8; j++) {
            int f = st + j * 16;
            int k = f >> 1, h4 = (f & 1) * 4;
            bool msk = (mreg[j] != 0);
#pragma unroll
            for (int c = 0; c < 4; c++)
                Bs[(h4 + c) * PLST + sq * 66 + k] = msk ? -3e38f : breg[j][c];
        }
        // (5) staged tile visible to all waves
        __syncthreads();
        // (6) scale+bias, online softmax, P->LDS, PV
#pragma unroll
        for (int mf = 0; mf < 2; mf++) {
#pragma unroll
            for (int r = 0; r < 4; r++) {
                int qrow = mf * 16 + lg * 4 + r;
#pragma unroll
                for (int kf = 0; kf < 4; kf++) {
                    int k = kf * 16 + lr;
                    s[mf][kf][r] = s[mf][kf][r] * 8.0f + Bw[qrow * 66 + k];
                }
            }
        }
#pragma unroll
        for (int mf = 0; mf < 2; mf++) {
#pragma unroll
            for (int r = 0; r < 4; r++) {
                float pm = s[mf][0][r];
#pragma unroll
                for (int kf = 1; kf < 4; kf++) pm = fmaxf(pm, s[mf][kf][r]);
                pm = fmaxf(pm, __shfl_xor(pm, 1));
                pm = fmaxf(pm, __shfl_xor(pm, 2));
                pm = fmaxf(pm, __shfl_xor(pm, 4));
                pm = fmaxf(pm, __shfl_xor(pm, 8));
                float mn = fmaxf(m_run[mf][r], pm);
                float fac = __expf(m_run[mf][r] - mn);
                m_run[mf][r] = mn;
                float rs = 0.f;
#pragma unroll
                for (int kf = 0; kf < 4; kf++) {
                    float p = __expf(s[mf][kf][r] - mn);
                    s[mf][kf][r] = p;
                    rs += p;
                }
                rs += __shfl_xor(rs, 1); rs += __shfl_xor(rs, 2);
                rs += __shfl_xor(rs, 4); rs += __shfl_xor(rs, 8);
                l_run[mf][r] = l_run[mf][r] * fac + rs;
#pragma unroll
                for (int df = 0; df < 4; df++) of[mf][df][r] *= fac;
            }
        }
#pragma unroll
        for (int mf = 0; mf < 2; mf++)
#pragma unroll
            for (int kf = 0; kf < 4; kf++)
#pragma unroll
                for (int r = 0; r < 4; r++)
                    Pw[(mf * 16 + lg * 4 + r) * PST + kf * 16 + lr] = f2bf(s[mf][kf][r]);
#pragma unroll
        for (int kk = 0; kk < 2; kk++) {
            bf16x8 pa[2];
#pragma unroll
            for (int mf = 0; mf < 2; mf++)
                pa[mf] = *reinterpret_cast<const bf16x8*>(
                    &Pw[(mf * 16 + lr) * PST + kk * 32 + lg * 8]);
#pragma unroll
            for (int df = 0; df < 4; df++) {
                bf16x8 vb = *reinterpret_cast<const bf16x8*>(
                    &Vp[(long)(df * 16 + lr) * 512 + k0 + kk * 32 + lg * 8]);
                of[0][df] = mfma16(pa[0], vb, of[0][df]);
                of[1][df] = mfma16(pa[1], vb, of[1][df]);
            }
        }
    }
    // epilogue
#pragma unroll
    for (int mf = 0; mf < 2; mf++) {
#pragma unroll
        for (int r = 0; r < 4; r++) {
            int q = bq0 + mf * 16 + lg * 4 + r;
            float inv = 1.0f / l_run[mf][r];
            u16* crow = ctx + ((long)b * 512 + q) * 512 + w * 64;
#pragma unroll
            for (int df = 0; df < 4; df++)
                crow[df * 16 + lr] = f2bf(of[mf][df][r] * inv);
        }
    }
}

// ---------------------------------------------------------------- layernorm
template<int WB>
__global__ __launch_bounds__(256) void ln_kernel(
    const float* __restrict__ xin, const float* __restrict__ g,
    const float* __restrict__ bta, float* __restrict__ fout, u16* __restrict__ bout)
{
    const int tid = threadIdx.x;
    const int w = tid >> 6, lane = tid & 63;
    const long row = (long)blockIdx.x * 4 + w;
    const float* xp = xin + row * 512 + lane * 8;
    f32x4 v0 = *(const f32x4*)(xp);
    f32x4 v1 = *(const f32x4*)(xp + 4);
    float sum = v0[0] + v0[1] + v0[2] + v0[3] + v1[0] + v1[1] + v1[2] + v1[3];
    float sq = v0[0]*v0[0] + v0[1]*v0[1] + v0[2]*v0[2] + v0[3]*v0[3]
             + v1[0]*v1[0] + v1[1]*v1[1] + v1[2]*v1[2] + v1[3]*v1[3];
#pragma unroll
    for (int m = 1; m <= 32; m <<= 1) {
        sum += __shfl_xor(sum, m);
        sq  += __shfl_xor(sq, m);
    }
    float mu = sum * (1.f / 512.f);
    float var = sq * (1.f / 512.f) - mu * mu;
    float rstd = rsqrtf(var + 1e-5f);
#pragma unroll
    for (int j = 0; j < 8; j++) {
        int c = lane * 8 + j;
        float x = (j < 4) ? v0[j] : v1[j - 4];
        float y = (x - mu) * rstd * g[c] + bta[c];
        fout[row * 512 + c] = y;
        if (WB) bout[row * 512 + c] = f2bf(y);
    }
}

// ---------------------------------------------------------------- launch
extern "C" void kernel_launch(void* const* d_in, const int* in_sizes, int n_in,
                              void* d_out, int out_size, void* d_ws, size_t ws_size,
                              hipStream_t stream)
{
    const float* nfeat     = (const float*)d_in[0];
    const float* attn_bias = (const float*)d_in[1];
    const int*   attn_mask = (const int*)d_in[2];
    const float* Wq = (const float*)d_in[3];
    const float* bq = (const float*)d_in[4];
    const float* Wk = (const float*)d_in[5];
    const float* bk = (const float*)d_in[6];
    const float* Wv = (const float*)d_in[7];
    const float* bv = (const float*)d_in[8];
    const float* Wo = (const float*)d_in[9];
    const float* bo = (const float*)d_in[10];
    const float* W1 = (const float*)d_in[11];
    const float* b1 = (const float*)d_in[12];
    const float* W2 = (const float*)d_in[13];
    const float* b2 = (const float*)d_in[14];
    const float* ln1_g = (const float*)d_in[15];
    const float* ln1_b = (const float*)d_in[16];
    const float* ln2_g = (const float*)d_in[17];
    const float* ln2_b = (const float*)d_in[18];

    char* ws = (char*)d_ws;
    size_t off = 0;
    auto alloc = [&](size_t bytes) -> void* {
        void* p = ws + off;
        off += (bytes + 255) & ~(size_t)255;
        return p;
    };
    u16* xh    = (u16*)alloc((size_t)M_ * D_ * 2);
    u16* xl    = (u16*)alloc((size_t)M_ * D_ * 2);
    u16* wqh   = (u16*)alloc((size_t)1536 * 512 * 2);
    u16* wql   = (u16*)alloc((size_t)1536 * 512 * 2);
    u16* wob   = (u16*)alloc((size_t)512 * 512 * 2);
    u16* w1b   = (u16*)alloc((size_t)2048 * 512 * 2);
    u16* w2b   = (u16*)alloc((size_t)512 * 2048 * 2);
    float* bqkv = (float*)alloc(1536 * 4);
    u16* Qh    = (u16*)alloc((size_t)B_ * H_ * N_ * DH_ * 2);
    u16* Ql    = (u16*)alloc((size_t)B_ * H_ * N_ * DH_ * 2);
    u16* Kh    = (u16*)alloc((size_t)B_ * H_ * N_ * DH_ * 2);
    u16* Kl    = (u16*)alloc((size_t)B_ * H_ * N_ * DH_ * 2);
    u16* Vt    = (u16*)alloc((size_t)B_ * H_ * N_ * DH_ * 2);
    u16* ctx   = (u16*)alloc((size_t)M_ * D_ * 2);
    float* xres = (float*)alloc((size_t)M_ * D_ * 4);
    float* x1f  = (float*)alloc((size_t)M_ * D_ * 4);
    u16* x1b   = (u16*)alloc((size_t)M_ * D_ * 2);
    u16* hb    = (u16*)alloc((size_t)M_ * HID_ * 2);

    convert_all<<<7170, 256, 0, stream>>>(nfeat, Wq, Wk, Wv, Wo, W1, W2, bq, bk, bv,
                                          xh, xl, wqh, wql, wob, w1b, w2b, bqkv);
    gemm_qkv<<<(M_/BM) * (1536/BN), 256, 0, stream>>>(
        xh, xl, wqh, wql, bqkv, Qh, Ql, Kh, Kl, Vt);
    // attention: 256 blocks = (b, 32-row q-tile), 8 waves = 8 heads
    attn_kernel<<<B_ * 16, 512, 0, stream>>>(
        Qh, Ql, Kh, Kl, Vt, attn_bias, attn_mask, ctx);
    gemm_bt<1><<<(M_/BM) * (512/BN), 256, 0, stream>>>(
        ctx, wob, bo, nfeat, xres, nullptr, M_, 512, 512);
    ln_kernel<1><<<M_ / 4, 256, 0, stream>>>(xres, ln1_g, ln1_b, x1f, x1b);
    gemm_bt<2><<<(M_/BM) * (HID_/BN), 256, 0, stream>>>(
        x1b, w1b, b1, nullptr, nullptr, hb, M_, HID_, 512);
    gemm_bt<1><<<(M_/BM) * (512/BN), 256, 0, stream>>>(
        hb, w2b, b2, x1f, xres, nullptr, M_, 512, 2048);
    ln_kernel<0><<<M_ / 4, 256, 0, stream>>>(xres, ln2_g, ln2_b, (float*)d_out, nullptr);
}

// Round 7
// 504.233 us; speedup vs baseline: 1.0908x; 1.0243x over previous
//
#include <hip/hip_runtime.h>
#include <hip/hip_bf16.h>
#include <stdint.h>

typedef unsigned short u16;
typedef __attribute__((ext_vector_type(8))) __bf16 bf16x8;
typedef __attribute__((ext_vector_type(4))) float f32x4;
typedef __attribute__((ext_vector_type(4))) unsigned short u16x4;

#define B_   16
#define N_   512
#define D_   512
#define H_   8
#define DH_  64
#define HID_ 2048
#define M_   8192   // B_*N_
#define FRAG_BH 32768   // per-(b,h) elements of each frag-major buffer

__device__ __forceinline__ u16 f2bf(float f) {
    unsigned u = __float_as_uint(f);
    u += 0x7fffu + ((u >> 16) & 1u);
    return (u16)(u >> 16);
}
__device__ __forceinline__ float bf2f(u16 u) {
    return __uint_as_float(((unsigned)u) << 16);
}
__device__ __forceinline__ f32x4 mfma16(bf16x8 a, bf16x8 b, f32x4 c) {
    return __builtin_amdgcn_mfma_f32_16x16x32_bf16(a, b, c, 0, 0, 0);
}
__device__ __forceinline__ void gload_lds16(const u16* g, u16* l) {
    __builtin_amdgcn_global_load_lds(
        (const __attribute__((address_space(1))) void*)g,
        (__attribute__((address_space(3))) void*)l, 16, 0, 0);
}

// ---------------------------------------------------------------- convert
__device__ __forceinline__ void cvt4(const float* s, u16* d) {
    f32x4 v = *(const f32x4*)s;
    u16x4 o;
    o[0] = f2bf(v[0]); o[1] = f2bf(v[1]); o[2] = f2bf(v[2]); o[3] = f2bf(v[3]);
    *(u16x4*)d = o;
}
__device__ __forceinline__ void cvt4s(const float* s, u16* dh, u16* dl) {
    f32x4 v = *(const f32x4*)s;
    u16x4 oh, ol;
#pragma unroll
    for (int j = 0; j < 4; j++) {
        oh[j] = f2bf(v[j]);
        float r = v[j] - bf2f(oh[j]);
        ol[j] = f2bf(r);
    }
    *(u16x4*)dh = oh;
    *(u16x4*)dl = ol;
}

__global__ __launch_bounds__(256) void convert_all(
    const float* __restrict__ nf, const float* __restrict__ Wq,
    const float* __restrict__ Wk, const float* __restrict__ Wv,
    const float* __restrict__ Wo, const float* __restrict__ W1,
    const float* __restrict__ W2, const float* __restrict__ bq,
    const float* __restrict__ bk, const float* __restrict__ bv,
    u16* __restrict__ xh, u16* __restrict__ xl,
    u16* __restrict__ wqh, u16* __restrict__ wql,
    u16* __restrict__ wob, u16* __restrict__ w1b, u16* __restrict__ w2b,
    float* __restrict__ bqkv)
{
    long i = ((long)blockIdx.x * 256 + threadIdx.x) * 4;
    if (i < 4194304) { cvt4s(nf + i, xh + i, xl + i); return; }
    i -= 4194304;
    if (i < 786432) {
        const float* s = (i < 262144) ? (Wq + i)
                       : (i < 524288) ? (Wk + i - 262144) : (Wv + i - 524288);
        cvt4s(s, wqh + i, wql + i); return;
    }
    i -= 786432;
    if (i < 262144) { cvt4(Wo + i, wob + i); return; }
    i -= 262144;
    if (i < 1048576) { cvt4(W1 + i, w1b + i); return; }
    i -= 1048576;
    if (i < 1048576) { cvt4(W2 + i, w2b + i); return; }
    i -= 1048576;
    if (i < 1536) {
        const float* s = (i < 512) ? (bq + i) : (i < 1024 ? bk + i - 512 : bv + i - 1024);
        *(f32x4*)(bqkv + i) = *(const f32x4*)s;
    }
}

#define BM 128
#define BN 128
#define BK 32

// ------------------------------------------------- split-precision QKV GEMM
// Epilogue writes FRAGMENT-MAJOR Q/K (hi+lo) and V so attention loads are
// single coalesced 1KB transactions.
// Q/K: idx = bh*32768 + ((nb*2+kk)*64 + gam*16+rho)*8 + e
//      nb=nn>>4, rho=nn&15, kk=dh>>5, gam=(dh>>3)&3, e=dh&7
// V:   idx = bh*32768 + ((nb32*4+df)*64 + gam*16+rho)*8 + e
//      nb32=nn>>5, gam=(nn>>3)&3, e=nn&7, df=dh>>4, rho=dh&15
__global__ __launch_bounds__(256) void gemm_qkv(
    const u16* __restrict__ Ah, const u16* __restrict__ Al,
    const u16* __restrict__ Wh, const u16* __restrict__ Wl,
    const float* __restrict__ bias,
    u16* __restrict__ Qf, u16* __restrict__ Qlf,
    u16* __restrict__ Kf, u16* __restrict__ Klf, u16* __restrict__ Vf)
{
    __shared__ u16 sAh[BM * BK], sAl[BM * BK], sBh[BN * BK], sBl[BN * BK];
    const int Kdim = 512;
    const int tid = threadIdx.x;
    const int w = tid >> 6, lane = tid & 63;
    const int lr = lane & 15, lg = lane >> 4;
    const int nTn = 1536 / BN;
    const int tm = blockIdx.x / nTn, tn = blockIdx.x % nTn;
    const long m0 = (long)tm * BM, n0 = (long)tn * BN;
    const int which = (int)(n0 >> 9);      // 0=Q 1=K 2=V, block-uniform
    const bool vpath = (which == 2);

    f32x4 acc[4][4];
#pragma unroll
    for (int i = 0; i < 4; i++)
#pragma unroll
        for (int j = 0; j < 4; j++) acc[i][j] = (f32x4){0.f, 0.f, 0.f, 0.f};

    const int e0 = w * 512 + lane * 8;
    const int r0 = e0 >> 5, c0 = e0 & 31;
    const int r1 = r0 + 64;
    const long gA0 = (long)r0 * Kdim + c0, gA1 = (long)r1 * Kdim + c0;
    const u16* pAh = Ah + m0 * Kdim;
    const u16* pAl = Al + m0 * Kdim;
    const u16* pBh = Wh + n0 * Kdim;
    const u16* pBl = Wl + n0 * Kdim;
    u16* dAh0 = sAh + w * 512; u16* dAh1 = sAh + w * 512 + 2048;
    u16* dAl0 = sAl + w * 512; u16* dAl1 = sAl + w * 512 + 2048;
    u16* dBh0 = sBh + w * 512; u16* dBh1 = sBh + w * 512 + 2048;
    u16* dBl0 = sBl + w * 512; u16* dBl1 = sBl + w * 512 + 2048;

    const int wr = (w >> 1) * 64, wc = (w & 1) * 64;

    for (int k0 = 0; k0 < Kdim; k0 += BK) {
        gload_lds16(pAh + gA0 + k0, dAh0);
        gload_lds16(pAh + gA1 + k0, dAh1);
        gload_lds16(pBh + gA0 + k0, dBh0);
        gload_lds16(pBh + gA1 + k0, dBh1);
        if (!vpath) {
            gload_lds16(pAl + gA0 + k0, dAl0);
            gload_lds16(pAl + gA1 + k0, dAl1);
            gload_lds16(pBl + gA0 + k0, dBl0);
            gload_lds16(pBl + gA1 + k0, dBl1);
        }
        __syncthreads();
        bf16x8 ah[4], bh[4];
#pragma unroll
        for (int i = 0; i < 4; i++) {
            int ra = (wr + i * 16 + lr) * BK + lg * 8;
            int rb = (wc + i * 16 + lr) * BK + lg * 8;
            ah[i] = *reinterpret_cast<const bf16x8*>(&sAh[ra]);
            bh[i] = *reinterpret_cast<const bf16x8*>(&sBh[rb]);
        }
        if (vpath) {
#pragma unroll
            for (int i = 0; i < 4; i++)
#pragma unroll
                for (int j = 0; j < 4; j++)
                    acc[i][j] = mfma16(ah[i], bh[j], acc[i][j]);
        } else {
            bf16x8 al[4], bl[4];
#pragma unroll
            for (int i = 0; i < 4; i++) {
                int ra = (wr + i * 16 + lr) * BK + lg * 8;
                int rb = (wc + i * 16 + lr) * BK + lg * 8;
                al[i] = *reinterpret_cast<const bf16x8*>(&sAl[ra]);
                bl[i] = *reinterpret_cast<const bf16x8*>(&sBl[rb]);
            }
#pragma unroll
            for (int i = 0; i < 4; i++)
#pragma unroll
                for (int j = 0; j < 4; j++) {
                    acc[i][j] = mfma16(ah[i], bh[j], acc[i][j]);
                    acc[i][j] = mfma16(ah[i], bl[j], acc[i][j]);
                    acc[i][j] = mfma16(al[i], bh[j], acc[i][j]);
                }
        }
        __syncthreads();
    }

#pragma unroll
    for (int i = 0; i < 4; i++) {
#pragma unroll
        for (int j = 0; j < 4; j++) {
#pragma unroll
            for (int r = 0; r < 4; r++) {
                long m = m0 + wr + i * 16 + lg * 4 + r;
                long n = n0 + wc + j * 16 + lr;
                float v = acc[i][j][r] + bias[n];
                int b = (int)(m >> 9), nn = (int)(m & 511);
                int h = ((int)n >> 6) & 7, dh = (int)n & 63;
                long bh_ = (long)b * 8 + h;
                if (which == 2) {
                    int df = dh >> 4, rho = dh & 15;
                    int gam = (nn >> 3) & 3, e = nn & 7, nb32 = nn >> 5;
                    Vf[bh_ * FRAG_BH + (((long)nb32 * 4 + df) * 64 + gam * 16 + rho) * 8 + e]
                        = f2bf(v);
                } else {
                    int nb = nn >> 4, rho = nn & 15;
                    int kk = dh >> 5, gam = (dh >> 3) & 3, e = dh & 7;
                    long idx = bh_ * FRAG_BH + (((long)nb * 2 + kk) * 64 + gam * 16 + rho) * 8 + e;
                    u16 hi = f2bf(v);
                    u16 lo = f2bf(v - bf2f(hi));
                    if (which == 0) { Qf[idx] = hi; Qlf[idx] = lo; }
                    else            { Kf[idx] = hi; Klf[idx] = lo; }
                }
            }
        }
    }
}

// ---------------------------------------------------------------- GEMM (bf16)
template<int EPI>
__global__ __launch_bounds__(256) void gemm_bt(
    const u16* __restrict__ A, const u16* __restrict__ W,
    const float* __restrict__ bias, const float* __restrict__ resid,
    float* __restrict__ outf, u16* __restrict__ outb,
    int Mdim, int Ndim, int Kdim)
{
    __shared__ u16 As[BM * BK];
    __shared__ u16 Bs[BN * BK];
    const int tid = threadIdx.x;
    const int w = tid >> 6, lane = tid & 63;
    const int lr = lane & 15, lg = lane >> 4;
    const int nTn = Ndim / BN;
    const int tm = blockIdx.x / nTn, tn = blockIdx.x % nTn;
    const long m0 = (long)tm * BM, n0 = (long)tn * BN;

    f32x4 acc[4][4];
#pragma unroll
    for (int i = 0; i < 4; i++)
#pragma unroll
        for (int j = 0; j < 4; j++) acc[i][j] = (f32x4){0.f, 0.f, 0.f, 0.f};

    const int e0 = w * 512 + lane * 8;
    const int r0 = e0 >> 5, c0 = e0 & 31;
    const int r1 = r0 + 64, c1 = c0;
    u16* As0 = As + w * 512;
    u16* As1 = As + w * 512 + 2048;
    u16* Bs0 = Bs + w * 512;
    u16* Bs1 = Bs + w * 512 + 2048;
    const u16* Ag = A + m0 * Kdim;
    const u16* Bg = W + n0 * Kdim;

    const int wr = (w >> 1) * 64, wc = (w & 1) * 64;

    for (int k0 = 0; k0 < Kdim; k0 += BK) {
        gload_lds16(Ag + (long)r0 * Kdim + k0 + c0, As0);
        gload_lds16(Ag + (long)r1 * Kdim + k0 + c1, As1);
        gload_lds16(Bg + (long)r0 * Kdim + k0 + c0, Bs0);
        gload_lds16(Bg + (long)r1 * Kdim + k0 + c1, Bs1);
        __syncthreads();
        bf16x8 af[4], bfr[4];
#pragma unroll
        for (int i = 0; i < 4; i++) {
            af[i]  = *reinterpret_cast<const bf16x8*>(&As[(wr + i * 16 + lr) * BK + lg * 8]);
            bfr[i] = *reinterpret_cast<const bf16x8*>(&Bs[(wc + i * 16 + lr) * BK + lg * 8]);
        }
#pragma unroll
        for (int i = 0; i < 4; i++)
#pragma unroll
            for (int j = 0; j < 4; j++)
                acc[i][j] = mfma16(af[i], bfr[j], acc[i][j]);
        __syncthreads();
    }

#pragma unroll
    for (int i = 0; i < 4; i++) {
#pragma unroll
        for (int j = 0; j < 4; j++) {
#pragma unroll
            for (int r = 0; r < 4; r++) {
                long m = m0 + wr + i * 16 + lg * 4 + r;
                long n = n0 + wc + j * 16 + lr;
                float v = acc[i][j][r];
                if (EPI == 1) {
                    long idx = m * Ndim + n;
                    outf[idx] = v + bias[n] + resid[idx];
                } else {
                    float t = v + bias[n];
                    t = t > 0.f ? t : 0.f;
                    outb[m * Ndim + n] = f2bf(t);
                }
            }
        }
    }
}

// ---------------------------------------------------------------- attention
// 512 blocks = (b, 16-row q-tile); 8 waves = 8 heads; ~52KB LDS -> 2-3 blk/CU.
// Frag-major Q/K/V global loads (1KB coalesced). Bias reg-double-buffered.
#define PLST 1060   // per-head bias plane stride in f32 ([16][66] + 4 pad)
#define PST  72     // P LDS row stride (u16)

__global__ __launch_bounds__(512) void attn_kernel(
    const u16* __restrict__ Qf, const u16* __restrict__ Qlf,
    const u16* __restrict__ Kf, const u16* __restrict__ Klf,
    const u16* __restrict__ Vf,
    const float* __restrict__ bias, const int* __restrict__ mask,
    u16* __restrict__ ctx)
{
    __shared__ float Bs[8 * PLST];      // 33920 B
    __shared__ u16 Ps[8 * 16 * PST];    // 18432 B
    const int tid = threadIdx.x;
    const int w = tid >> 6, lane = tid & 63;
    const int lr = lane & 15, lg = lane >> 4;
    const int b = blockIdx.x >> 5, qt = blockIdx.x & 31;
    const int bq0 = qt * 16;
    const long bh = (long)b * 8 + w;    // wave w == head w
    const u16* Qfp  = Qf  + bh * FRAG_BH;
    const u16* Qlfp = Qlf + bh * FRAG_BH;
    const u16* Kfp  = Kf  + bh * FRAG_BH;
    const u16* Klfp = Klf + bh * FRAG_BH;
    const u16* Vfp  = Vf  + bh * FRAG_BH;

    // staging ids: thread -> (q-row sq 0..15, 32-slot st)
    const int sq = tid >> 5, st = tid & 31;
    const float* bias_row = bias + ((long)b * 512 + bq0 + sq) * 512 * 8;
    const int*   mask_row = mask + ((long)b * 512 + bq0 + sq) * 512;

    bf16x8 qhf[2], qlf[2];
#pragma unroll
    for (int kk = 0; kk < 2; kk++) {
        long off = (((long)qt * 2 + kk) * 64 + lane) * 8;
        qhf[kk] = *reinterpret_cast<const bf16x8*>(&Qfp[off]);
        qlf[kk] = *reinterpret_cast<const bf16x8*>(&Qlfp[off]);
    }

    f32x4 of[4];
    float m_run[4], l_run[4];
#pragma unroll
    for (int df = 0; df < 4; df++) of[df] = (f32x4){0.f, 0.f, 0.f, 0.f};
#pragma unroll
    for (int r = 0; r < 4; r++) { m_run[r] = -1e30f; l_run[r] = 0.f; }

    float* Bw = Bs + w * PLST;
    u16* Pw = Ps + w * 16 * PST;

    f32x4 bA[4], bB[4];
    int mA[4], mB[4];

    auto loadbias = [&](int kt, f32x4 (&bb)[4], int (&mm)[4]) {
#pragma unroll
        for (int j = 0; j < 4; j++) {
            int f = st + j * 32;
            bb[j] = *(const f32x4*)(bias_row + (long)kt * 512 + f * 4);
            mm[j] = mask_row[kt * 64 + (f >> 1)];
        }
    };

    auto body = [&](int kt, f32x4 (&bc)[4], int (&mc)[4],
                    f32x4 (&bn)[4], int (&mn)[4], bool pf) {
        // ---- QK^T (frag-major coalesced K loads, hi/lo 3-term)
        f32x4 s[4];
#pragma unroll
        for (int kf = 0; kf < 4; kf++) s[kf] = (f32x4){0.f, 0.f, 0.f, 0.f};
#pragma unroll
        for (int kf = 0; kf < 4; kf++) {
            long kb = (((long)(kt * 4 + kf) * 2) * 64 + lane) * 8;
            bf16x8 kh0 = *reinterpret_cast<const bf16x8*>(&Kfp[kb]);
            bf16x8 kh1 = *reinterpret_cast<const bf16x8*>(&Kfp[kb + 512]);
            bf16x8 kl0 = *reinterpret_cast<const bf16x8*>(&Klfp[kb]);
            bf16x8 kl1 = *reinterpret_cast<const bf16x8*>(&Klfp[kb + 512]);
            __builtin_amdgcn_s_setprio(1);
            s[kf] = mfma16(qhf[0], kh0, s[kf]);
            s[kf] = mfma16(qhf[1], kh1, s[kf]);
            s[kf] = mfma16(qhf[0], kl0, s[kf]);
            s[kf] = mfma16(qhf[1], kl1, s[kf]);
            s[kf] = mfma16(qlf[0], kh0, s[kf]);
            s[kf] = mfma16(qlf[1], kh1, s[kf]);
            __builtin_amdgcn_s_setprio(0);
        }
        // ---- bias regs -> LDS (prev consumers done)
        __syncthreads();
#pragma unroll
        for (int j = 0; j < 4; j++) {
            int f = st + j * 32;
            int k = f >> 1, h4 = (f & 1) * 4;
            bool msk = (mc[j] != 0);
#pragma unroll
            for (int c = 0; c < 4; c++)
                Bs[(h4 + c) * PLST + sq * 66 + k] = msk ? -3e38f : bc[j][c];
        }
        __syncthreads();
        // ---- prefetch next tile's bias/mask (overlaps softmax+PV)
        if (pf) loadbias(kt + 1, bn, mn);
        // ---- scale + bias, online softmax (rows lg*4+r)
#pragma unroll
        for (int r = 0; r < 4; r++) {
            int qrow = lg * 4 + r;
#pragma unroll
            for (int kf = 0; kf < 4; kf++)
                s[kf][r] = s[kf][r] * 8.0f + Bw[qrow * 66 + kf * 16 + lr];
        }
#pragma unroll
        for (int r = 0; r < 4; r++) {
            float pm = fmaxf(fmaxf(s[0][r], s[1][r]), fmaxf(s[2][r], s[3][r]));
            pm = fmaxf(pm, __shfl_xor(pm, 1));
            pm = fmaxf(pm, __shfl_xor(pm, 2));
            pm = fmaxf(pm, __shfl_xor(pm, 4));
            pm = fmaxf(pm, __shfl_xor(pm, 8));
            float mn_ = fmaxf(m_run[r], pm);
            float fac = __expf(m_run[r] - mn_);
            m_run[r] = mn_;
            float rs = 0.f;
#pragma unroll
            for (int kf = 0; kf < 4; kf++) {
                float p = __expf(s[kf][r] - mn_);
                s[kf][r] = p;
                rs += p;
            }
            rs += __shfl_xor(rs, 1); rs += __shfl_xor(rs, 2);
            rs += __shfl_xor(rs, 4); rs += __shfl_xor(rs, 8);
            l_run[r] = l_run[r] * fac + rs;
#pragma unroll
            for (int df = 0; df < 4; df++) of[df][r] *= fac;
        }
        // ---- P -> LDS (wave-private)
#pragma unroll
        for (int kf = 0; kf < 4; kf++)
#pragma unroll
            for (int r = 0; r < 4; r++)
                Pw[(lg * 4 + r) * PST + kf * 16 + lr] = f2bf(s[kf][r]);
        // ---- PV (frag-major coalesced V loads)
#pragma unroll
        for (int kk = 0; kk < 2; kk++) {
            bf16x8 pa = *reinterpret_cast<const bf16x8*>(
                &Pw[lr * PST + kk * 32 + lg * 8]);
#pragma unroll
            for (int df = 0; df < 4; df++) {
                bf16x8 vb = *reinterpret_cast<const bf16x8*>(
                    &Vfp[((((long)(kt * 2 + kk)) * 4 + df) * 64 + lane) * 8]);
                __builtin_amdgcn_s_setprio(1);
                of[df] = mfma16(pa, vb, of[df]);
                __builtin_amdgcn_s_setprio(0);
            }
        }
    };

    loadbias(0, bA, mA);
#pragma unroll
    for (int kt2 = 0; kt2 < 4; kt2++) {
        body(kt2 * 2,     bA, mA, bB, mB, true);
        body(kt2 * 2 + 1, bB, mB, bA, mA, kt2 < 3);
    }

    // epilogue: rows bq0 + lg*4 + r
#pragma unroll
    for (int r = 0; r < 4; r++) {
        int q = bq0 + lg * 4 + r;
        float inv = 1.0f / l_run[r];
        u16* crow = ctx + ((long)b * 512 + q) * 512 + w * 64;
#pragma unroll
        for (int df = 0; df < 4; df++)
            crow[df * 16 + lr] = f2bf(of[df][r] * inv);
    }
}

// ---------------------------------------------------------------- layernorm
template<int WB>
__global__ __launch_bounds__(256) void ln_kernel(
    const float* __restrict__ xin, const float* __restrict__ g,
    const float* __restrict__ bta, float* __restrict__ fout, u16* __restrict__ bout)
{
    const int tid = threadIdx.x;
    const int w = tid >> 6, lane = tid & 63;
    const long row = (long)blockIdx.x * 4 + w;
    const float* xp = xin + row * 512 + lane * 8;
    f32x4 v0 = *(const f32x4*)(xp);
    f32x4 v1 = *(const f32x4*)(xp + 4);
    float sum = v0[0] + v0[1] + v0[2] + v0[3] + v1[0] + v1[1] + v1[2] + v1[3];
    float sq = v0[0]*v0[0] + v0[1]*v0[1] + v0[2]*v0[2] + v0[3]*v0[3]
             + v1[0]*v1[0] + v1[1]*v1[1] + v1[2]*v1[2] + v1[3]*v1[3];
#pragma unroll
    for (int m = 1; m <= 32; m <<= 1) {
        sum += __shfl_xor(sum, m);
        sq  += __shfl_xor(sq, m);
    }
    float mu = sum * (1.f / 512.f);
    float var = sq * (1.f / 512.f) - mu * mu;
    float rstd = rsqrtf(var + 1e-5f);
#pragma unroll
    for (int j = 0; j < 8; j++) {
        int c = lane * 8 + j;
        float x = (j < 4) ? v0[j] : v1[j - 4];
        float y = (x - mu) * rstd * g[c] + bta[c];
        fout[row * 512 + c] = y;
        if (WB) bout[row * 512 + c] = f2bf(y);
    }
}

// ---------------------------------------------------------------- launch
extern "C" void kernel_launch(void* const* d_in, const int* in_sizes, int n_in,
                              void* d_out, int out_size, void* d_ws, size_t ws_size,
                              hipStream_t stream)
{
    const float* nfeat     = (const float*)d_in[0];
    const float* attn_bias = (const float*)d_in[1];
    const int*   attn_mask = (const int*)d_in[2];
    const float* Wq = (const float*)d_in[3];
    const float* bq = (const float*)d_in[4];
    const float* Wk = (const float*)d_in[5];
    const float* bk = (const float*)d_in[6];
    const float* Wv = (const float*)d_in[7];
    const float* bv = (const float*)d_in[8];
    const float* Wo = (const float*)d_in[9];
    const float* bo = (const float*)d_in[10];
    const float* W1 = (const float*)d_in[11];
    const float* b1 = (const float*)d_in[12];
    const float* W2 = (const float*)d_in[13];
    const float* b2 = (const float*)d_in[14];
    const float* ln1_g = (const float*)d_in[15];
    const float* ln1_b = (const float*)d_in[16];
    const float* ln2_g = (const float*)d_in[17];
    const float* ln2_b = (const float*)d_in[18];

    char* ws = (char*)d_ws;
    size_t off = 0;
    auto alloc = [&](size_t bytes) -> void* {
        void* p = ws + off;
        off += (bytes + 255) & ~(size_t)255;
        return p;
    };
    u16* xh    = (u16*)alloc((size_t)M_ * D_ * 2);
    u16* xl    = (u16*)alloc((size_t)M_ * D_ * 2);
    u16* wqh   = (u16*)alloc((size_t)1536 * 512 * 2);
    u16* wql   = (u16*)alloc((size_t)1536 * 512 * 2);
    u16* wob   = (u16*)alloc((size_t)512 * 512 * 2);
    u16* w1b   = (u16*)alloc((size_t)2048 * 512 * 2);
    u16* w2b   = (u16*)alloc((size_t)512 * 2048 * 2);
    float* bqkv = (float*)alloc(1536 * 4);
    u16* Qf    = (u16*)alloc((size_t)128 * FRAG_BH * 2);
    u16* Qlf   = (u16*)alloc((size_t)128 * FRAG_BH * 2);
    u16* Kf    = (u16*)alloc((size_t)128 * FRAG_BH * 2);
    u16* Klf   = (u16*)alloc((size_t)128 * FRAG_BH * 2);
    u16* Vf    = (u16*)alloc((size_t)128 * FRAG_BH * 2);
    u16* ctx   = (u16*)alloc((size_t)M_ * D_ * 2);
    float* xres = (float*)alloc((size_t)M_ * D_ * 4);
    float* x1f  = (float*)alloc((size_t)M_ * D_ * 4);
    u16* x1b   = (u16*)alloc((size_t)M_ * D_ * 2);
    u16* hb    = (u16*)alloc((size_t)M_ * HID_ * 2);

    convert_all<<<7170, 256, 0, stream>>>(nfeat, Wq, Wk, Wv, Wo, W1, W2, bq, bk, bv,
                                          xh, xl, wqh, wql, wob, w1b, w2b, bqkv);
    gemm_qkv<<<(M_/BM) * (1536/BN), 256, 0, stream>>>(
        xh, xl, wqh, wql, bqkv, Qf, Qlf, Kf, Klf, Vf);
    // attention: 512 blocks = (b, 16-row q-tile), 8 waves = 8 heads
    attn_kernel<<<B_ * 32, 512, 0, stream>>>(
        Qf, Qlf, Kf, Klf, Vf, attn_bias, attn_mask, ctx);
    gemm_bt<1><<<(M_/BM) * (512/BN), 256, 0, stream>>>(
        ctx, wob, bo, nfeat, xres, nullptr, M_, 512, 512);
    ln_kernel<1><<<M_ / 4, 256, 0, stream>>>(xres, ln1_g, ln1_b, x1f, x1b);
    gemm_bt<2><<<(M_/BM) * (HID_/BN), 256, 0, stream>>>(
        x1b, w1b, b1, nullptr, nullptr, hb, M_, HID_, 512);
    gemm_bt<1><<<(M_/BM) * (512/BN), 256, 0, stream>>>(
        hb, w2b, b2, x1f, xres, nullptr, M_, 512, 2048);
    ln_kernel<0><<<M_ / 4, 256, 0, stream>>>(xres, ln2_g, ln2_b, (float*)d_out, nullptr);
}